// Round 5
// baseline (184.568 us; speedup 1.0000x reference)
//
#include <hip/hip_runtime.h>
#include <hip/hip_bf16.h>
#include <math.h>

// Problem constants (B=2, C=256, H=W=64, NUM_HEADS=8, AREA=4)
#define CCH   256
#define NPIX  4096
#define NHD   8
#define HD    32
#define NA    1024
#define BN_EPS 1e-5f
#define ATT_SCALE 0.17677669529663687f   // 1/sqrt(32), folded into Q at qk_gemm

typedef __attribute__((ext_vector_type(8))) short bf16x8;
typedef __attribute__((ext_vector_type(4))) short bf16x4;
typedef __attribute__((ext_vector_type(4))) float f32x4;

static __device__ inline short f2bf(float f) {
    union { float f; unsigned u; } v; v.f = f;
    unsigned r = (v.u + 0x7fff + ((v.u >> 16) & 1)) >> 16;  // RNE
    return (short)r;
}

// packed RNE f32x2 -> bf16x2 (low = a, high = b)
static __device__ inline unsigned int pk2bf(float a, float b) {
    __hip_bfloat162 h2 = __float22bfloat162_rn(make_float2(a, b));
    union { __hip_bfloat162 h; unsigned int u; } v; v.h = h2;
    return v.u;
}

// ---------------------------------------------------------------------------
// Kernel: transpose+cast  x[b][c][n] f32  ->  Xt[b*4096+n][c] bf16
// grid (64, 4, 2), block 256. LDS tile 64x64, pad 66 halves (2-way = free).
// ---------------------------------------------------------------------------
__global__ __launch_bounds__(256)
void xt_kernel(const float* __restrict__ x, short* __restrict__ Xt) {
    __shared__ short tile[64][66];
    const int t  = threadIdx.x;
    const int n0 = blockIdx.x << 6;
    const int c0 = blockIdx.y << 6;
    const int b  = blockIdx.z;
    const float* xp = x + (((size_t)(b * CCH + c0)) << 12) + n0;
    #pragma unroll
    for (int j = 0; j < 16; ++j) {
        const int lin = (j << 8) + t;
        const int cl = lin >> 6, nl = lin & 63;
        tile[cl][nl] = f2bf(xp[((size_t)cl << 12) + nl]);
    }
    __syncthreads();
    short* xtp = Xt + ((((size_t)b << 12) + n0) << 8) + c0;
    #pragma unroll
    for (int j = 0; j < 16; ++j) {
        const int lin = (j << 8) + t;
        const int nl = lin >> 6, cl = lin & 63;
        xtp[((size_t)nl << 8) + cl] = tile[cl][nl];
    }
}

// ---------------------------------------------------------------------------
// Kernel: cast weights to bf16. Wb rows: [0,512)=w_qk, [512,768)=w_v,
// [768,1024)=w_p, each row 256. grid 256, block 256, 4 elems/thread.
// ---------------------------------------------------------------------------
__global__ __launch_bounds__(256)
void wcast_kernel(const float* __restrict__ wqk, const float* __restrict__ wv,
                  const float* __restrict__ wp, short* __restrict__ Wb) {
    const int idx = (blockIdx.x * 256 + threadIdx.x) * 4;
    const float* src; int off;
    if (idx < 131072)      { src = wqk; off = idx; }
    else if (idx < 196608) { src = wv;  off = idx - 131072; }
    else                   { src = wp;  off = idx - 196608; }
    const float4 v = *(const float4*)(src + off);
    short4 o;
    o.x = f2bf(v.x); o.y = f2bf(v.y); o.z = f2bf(v.z); o.w = f2bf(v.w);
    *(short4*)(Wb + idx) = o;
}

// ---------------------------------------------------------------------------
// Kernel: QK GEMM.  D[i][o] = sum_c Xt[i][c] * Wqk[o][c], i=0..8191, o=0..511.
// Wave tile 16x64 (4096 waves for latency hiding); 4 waves/block share the
// B (weight) panel via L1. grid (128, 8), block 256.
// Epilogue: BN (Q also folds ATT_SCALE), bf16, scatter to Qb/Kb[pair][i][d].
// ---------------------------------------------------------------------------
__global__ __launch_bounds__(256, 4)
void qk_gemm(const short* __restrict__ Xt, const short* __restrict__ Wb,
             const float* __restrict__ g_qk, const float* __restrict__ b_qk,
             const float* __restrict__ m_qk, const float* __restrict__ v_qk,
             short* __restrict__ Qb, short* __restrict__ Kb) {
    const int lane = threadIdx.x & 63;
    const int w    = threadIdx.x >> 6;
    const int c    = lane & 15;
    const int quad = lane >> 4;
    const int m0 = (blockIdx.x * 4 + w) * 16;
    const int n0 = blockIdx.y * 64;

    const short* ap = Xt + ((size_t)(m0 + c) << 8) + (quad << 3);
    const short* bp = Wb + ((size_t)(n0 + c) << 8) + (quad << 3);

    f32x4 acc[4];
    #pragma unroll
    for (int g = 0; g < 4; ++g) acc[g] = (f32x4){0.f, 0.f, 0.f, 0.f};

    #pragma unroll
    for (int k = 0; k < 256; k += 32) {
        bf16x8 af = *(const bf16x8*)(ap + k);
        bf16x8 bg[4];
        #pragma unroll
        for (int g = 0; g < 4; ++g) bg[g] = *(const bf16x8*)(bp + g * 4096 + k);
        #pragma unroll
        for (int g = 0; g < 4; ++g)
            acc[g] = __builtin_amdgcn_mfma_f32_16x16x32_bf16(af, bg[g], acc[g], 0, 0, 0);
    }

    const bool isQ = (n0 < 256);
    short* dst = isQ ? Qb : Kb;
    const float fold = isQ ? ATT_SCALE : 1.0f;
    #pragma unroll
    for (int g = 0; g < 4; ++g) {
        const int o  = n0 + g * 16 + c;
        const int cd = o & 255;
        const int h  = cd >> 5;
        const int d  = cd & 31;
        float s    = g_qk[o] * rsqrtf(v_qk[o] + BN_EPS);
        float beta = (b_qk[o] - m_qk[o] * s) * fold;
        s *= fold;
        #pragma unroll
        for (int r = 0; r < 4; ++r) {
            const int row  = m0 + (quad << 2) + r;   // global spatial
            const int pair = (row >> 10) * NHD + h;
            const int i    = row & 1023;
            dst[(((size_t)pair << 10) + i) * HD + d] = f2bf(acc[g][r] * s + beta);
        }
    }
}

// ---------------------------------------------------------------------------
// Kernel: V GEMM.  D[o][j] = sum_c Wv[o][c] * Xt[j][c]. Wave tile 16x64,
// grid (4, 128), block 256 (waves share the Xt panel).
// Epilogue -> Vb[pair][d][j] coalesced.
// ---------------------------------------------------------------------------
__global__ __launch_bounds__(256, 4)
void v_gemm(const short* __restrict__ Wv, const short* __restrict__ Xt,
            const float* __restrict__ g_v, const float* __restrict__ b_v,
            const float* __restrict__ m_v, const float* __restrict__ v_v,
            short* __restrict__ Vb) {
    const int lane = threadIdx.x & 63;
    const int w    = threadIdx.x >> 6;
    const int c    = lane & 15;
    const int quad = lane >> 4;
    const int m0 = (blockIdx.x * 4 + w) * 16;
    const int n0 = blockIdx.y * 64;

    const short* ap = Wv + ((size_t)(m0 + c) << 8) + (quad << 3);
    const short* bp = Xt + ((size_t)(n0 + c) << 8) + (quad << 3);

    f32x4 acc[4];
    #pragma unroll
    for (int g = 0; g < 4; ++g) acc[g] = (f32x4){0.f, 0.f, 0.f, 0.f};

    #pragma unroll
    for (int k = 0; k < 256; k += 32) {
        bf16x8 af = *(const bf16x8*)(ap + k);
        bf16x8 bg[4];
        #pragma unroll
        for (int g = 0; g < 4; ++g) bg[g] = *(const bf16x8*)(bp + g * 4096 + k);
        #pragma unroll
        for (int g = 0; g < 4; ++g)
            acc[g] = __builtin_amdgcn_mfma_f32_16x16x32_bf16(af, bg[g], acc[g], 0, 0, 0);
    }

    #pragma unroll
    for (int r = 0; r < 4; ++r) {
        const int o = m0 + (quad << 2) + r;   // v channel 0..255
        const float s    = g_v[o] * rsqrtf(v_v[o] + BN_EPS);
        const float beta = b_v[o] - m_v[o] * s;
        const int d = o & 31;
        const int hpair = o >> 5;
        #pragma unroll
        for (int g = 0; g < 4; ++g) {
            const int col  = n0 + g * 16 + c;          // global spatial
            const int pair = (col >> 10) * NHD + hpair;
            const int j    = col & 1023;
            Vb[((size_t)pair << 15) + (d << 10) + j] = f2bf(acc[g][r] * s + beta);
        }
    }
}

// ---------------------------------------------------------------------------
// Kernel: MFMA flash attention, no-max softmax, ZERO LDS.
// S computed transposed (A=K, B=Q) with permuted K rows so the exp'd scores
// land exactly in the PV A-fragment layout in-register (no LDS round-trip):
//   MFMA0 A rows: j = 8*(c>>2)+(c&3); MFMA1: +4  =>  lane (c,q) holds
//   P[i=c][j=8q..8q+7] after packing. Row-sum l is a per-lane scalar.
// XCD swizzle: bx&7 = h, so each pair's K/V (128 KB) stays in one XCD L2.
// grid 1024, block 256 (4 waves, each an independent 16-row Q tile).
// ---------------------------------------------------------------------------
__global__ __launch_bounds__(256, 4)
void attn_kernel(const short* __restrict__ Qb,
                 const short* __restrict__ Kb,
                 const short* __restrict__ Vb,
                 short* __restrict__ AOt) {
    const int tid  = threadIdx.x;
    const int wave = tid >> 6;
    const int lane = tid & 63;
    const int c    = lane & 15;
    const int quad = lane >> 4;

    // swizzled decode: bx = (p&7) + 8*(16*(p>>3) + blk)
    const int bx  = blockIdx.x;
    const int hi  = bx >> 3;                    // 0..127
    const int p   = (bx & 7) + ((hi >> 4) << 3);  // pair 0..63
    const int blk = hi & 15;                    // 4 i-tiles per block
    const int i0  = ((blk << 2) + wave) << 4;
    const int ba  = p >> 3;
    const int h   = p & 7;

    const short* qbase = Qb + ((size_t)p << 15);
    const short* kbase = Kb + ((size_t)p << 15);
    const short* vbase = Vb + ((size_t)p << 15);

    // Q fragment: B[k=d=quad*8+t][n=i=c]  (pre-scaled by 1/sqrt(32))
    bf16x8 qf = *(const bf16x8*)(qbase + ((i0 + c) << 5) + (quad << 3));

    // permuted K row offset: rows j0+perm (MFMA0) and j0+perm+4 (MFMA1)
    const int perm = ((c >> 2) << 3) + (c & 3);

    f32x4 acc0 = {0.f, 0.f, 0.f, 0.f};
    f32x4 acc1 = {0.f, 0.f, 0.f, 0.f};
    float lacc = 0.f;
    const f32x4 zero = {0.f, 0.f, 0.f, 0.f};

    #pragma unroll 2
    for (int j0 = 0; j0 < NA; j0 += 32) {
        // S^T tiles: A[m][k=d] = K[j0+sigma(m)][d], 16B contiguous
        bf16x8 kf0 = *(const bf16x8*)(kbase + ((j0 + perm) << 5) + (quad << 3));
        bf16x8 kf1 = *(const bf16x8*)(kbase + ((j0 + perm + 4) << 5) + (quad << 3));
        f32x4 s0 = __builtin_amdgcn_mfma_f32_16x16x32_bf16(kf0, qf, zero, 0, 0, 0);
        f32x4 s1 = __builtin_amdgcn_mfma_f32_16x16x32_bf16(kf1, qf, zero, 0, 0, 0);
        // lane (c,q): s0[r] = S[i=i0+c][j=j0+8q+r], s1[r] = ... j=j0+8q+4+r

        float p0[4], p1[4];
        #pragma unroll
        for (int r = 0; r < 4; ++r) { p0[r] = __expf(s0[r]); p1[r] = __expf(s1[r]); }
        lacc += (p0[0] + p0[1]) + (p0[2] + p0[3]) + (p1[0] + p1[1]) + (p1[2] + p1[3]);

        // pack P A-fragment in-register: k order t=0..7 -> p0[0..3], p1[0..3]
        union { unsigned int u[4]; bf16x8 v; } pf;
        pf.u[0] = pk2bf(p0[0], p0[1]);
        pf.u[1] = pk2bf(p0[2], p0[3]);
        pf.u[2] = pk2bf(p1[0], p1[1]);
        pf.u[3] = pk2bf(p1[2], p1[3]);

        // V tiles: B[k=j=quad*8+t][n=d] = V^T[d][j0+quad*8+t], 16B contiguous
        bf16x8 vf0 = *(const bf16x8*)(vbase + (c << 10) + j0 + (quad << 3));
        bf16x8 vf1 = *(const bf16x8*)(vbase + ((c + 16) << 10) + j0 + (quad << 3));

        acc0 = __builtin_amdgcn_mfma_f32_16x16x32_bf16(pf.v, vf0, acc0, 0, 0, 0);
        acc1 = __builtin_amdgcn_mfma_f32_16x16x32_bf16(pf.v, vf1, acc1, 0, 0, 0);
    }

    // l reduction: sum the 4 quads (each lane then holds l for i = i0 + (lane&15))
    lacc += __shfl_xor(lacc, 16);
    lacc += __shfl_xor(lacc, 32);

    // Epilogue: acc0[r] = O[i0+quad*4+r][d=c], acc1 -> d=c+16.
    // AOt[(ba<<10)+i][h*32+d] bf16, coalesced 32B segments.
    #pragma unroll
    for (int r = 0; r < 4; ++r) {
        const int row = i0 + (quad << 2) + r;
        const float lr = __shfl(lacc, (quad << 2) + r, 16);
        const float rl = 1.f / lr;
        const size_t base = ((((size_t)ba << 10) + row) << 8) + (h << 5);
        AOt[base + c]      = f2bf(acc0[r] * rl);
        AOt[base + c + 16] = f2bf(acc1[r] * rl);
    }
}

// ---------------------------------------------------------------------------
// Kernel: P GEMM. D[o][n] = sum_c Wp[o][c] * AOt[n][c]. Wave tile 16x64,
// grid (4, 128). Epilogue BN -> f32 out.
// ---------------------------------------------------------------------------
__global__ __launch_bounds__(256, 4)
void pconv_gemm(const short* __restrict__ Wp, const short* __restrict__ AOt,
                const float* __restrict__ g_p, const float* __restrict__ b_p,
                const float* __restrict__ m_p, const float* __restrict__ v_p,
                float* __restrict__ out) {
    const int lane = threadIdx.x & 63;
    const int w    = threadIdx.x >> 6;
    const int c    = lane & 15;
    const int quad = lane >> 4;
    const int m0 = (blockIdx.x * 4 + w) * 16;
    const int n0 = blockIdx.y * 64;

    const short* ap = Wp + ((size_t)(m0 + c) << 8) + (quad << 3);
    const short* bp = AOt + ((size_t)(n0 + c) << 8) + (quad << 3);

    f32x4 acc[4];
    #pragma unroll
    for (int g = 0; g < 4; ++g) acc[g] = (f32x4){0.f, 0.f, 0.f, 0.f};

    #pragma unroll
    for (int k = 0; k < 256; k += 32) {
        bf16x8 af = *(const bf16x8*)(ap + k);
        bf16x8 bg[4];
        #pragma unroll
        for (int g = 0; g < 4; ++g) bg[g] = *(const bf16x8*)(bp + g * 4096 + k);
        #pragma unroll
        for (int g = 0; g < 4; ++g)
            acc[g] = __builtin_amdgcn_mfma_f32_16x16x32_bf16(af, bg[g], acc[g], 0, 0, 0);
    }

    #pragma unroll
    for (int r = 0; r < 4; ++r) {
        const int o = m0 + (quad << 2) + r;
        const float s    = g_p[o] * rsqrtf(v_p[o] + BN_EPS);
        const float beta = b_p[o] - m_p[o] * s;
        #pragma unroll
        for (int g = 0; g < 4; ++g) {
            const int col = n0 + g * 16 + c;           // global spatial
            const int b = col >> 12, n = col & 4095;
            out[((size_t)(b * CCH + o) << 12) + n] = acc[g][r] * s + beta;
        }
    }
}

// ---------------------------------------------------------------------------
extern "C" void kernel_launch(void* const* d_in, const int* in_sizes, int n_in,
                              void* d_out, int out_size, void* d_ws, size_t ws_size,
                              hipStream_t stream) {
    const float* x    = (const float*)d_in[0];
    const float* w_qk = (const float*)d_in[1];
    const float* g_qk = (const float*)d_in[2];
    const float* b_qk = (const float*)d_in[3];
    const float* m_qk = (const float*)d_in[4];
    const float* v_qk = (const float*)d_in[5];
    const float* w_v  = (const float*)d_in[6];
    const float* g_v  = (const float*)d_in[7];
    const float* b_v  = (const float*)d_in[8];
    const float* m_v  = (const float*)d_in[9];
    const float* v_v  = (const float*)d_in[10];
    const float* w_p  = (const float*)d_in[11];
    const float* g_p  = (const float*)d_in[12];
    const float* b_p  = (const float*)d_in[13];
    const float* m_p  = (const float*)d_in[14];
    const float* v_p  = (const float*)d_in[15];

    // ws layout (shorts): Qb | Kb | Vb | Xt | Wb ; AOt aliases Xt (dead by attn)
    short* Qb  = (short*)d_ws;
    short* Kb  = Qb + 2097152;
    short* Vb  = Kb + 2097152;
    short* Xt  = Vb + 2097152;
    short* Wb  = Xt + 2097152;
    short* AOt = Xt;

    dim3 gx(64, 4, 2);
    xt_kernel<<<gx, 256, 0, stream>>>(x, Xt);
    wcast_kernel<<<256, 256, 0, stream>>>(w_qk, w_v, w_p, Wb);

    dim3 gqk(128, 8);
    qk_gemm<<<gqk, 256, 0, stream>>>(Xt, Wb, g_qk, b_qk, m_qk, v_qk, Qb, Kb);
    dim3 gv(4, 128);
    v_gemm<<<gv, 256, 0, stream>>>(Wb + 512 * 256, Xt, g_v, b_v, m_v, v_v, Vb);

    attn_kernel<<<1024, 256, 0, stream>>>(Qb, Kb, Vb, AOt);

    dim3 gp(4, 128);
    pconv_gemm<<<gp, 256, 0, stream>>>(Wb + 768 * 256, AOt, g_p, b_p, m_p, v_p, (float*)d_out);
}